// Round 10
// baseline (294.458 us; speedup 1.0000x reference)
//
#include <hip/hip_runtime.h>
#include <hip/hip_fp16.h>
#include <stdint.h>

// ---------------------------------------------------------------------------
// GCN 3-layer + edge weights.
// v10: XCD-affine feature-sliced gather. Gather is MSHR*latency-bound with a
//   12.8MB working set (30% L2 hit). Split each row into 4x64B slices; block b
//   handles slice (b%8)>>1 so each XCD's L2 only sees 3.2MB -> L2-resident.
//   Separate gather->aggb->GEMM (v5 structure), no binning.
// ---------------------------------------------------------------------------

#define NF 128

typedef unsigned short u16;
typedef unsigned int u32;
typedef __attribute__((ext_vector_type(8))) short short8;   // 8 bf16 = 16 B
typedef __attribute__((ext_vector_type(4))) float f32x4;

__device__ __forceinline__ float bf2f(u16 v) {
    union { unsigned u; float f; } x; x.u = (unsigned)v << 16; return x.f;
}
__device__ __forceinline__ u16 f2bf(float f) {
    union { float f; unsigned u; } x; x.f = f;
    unsigned r = (x.u + 0x7FFFu + ((x.u >> 16) & 1u)) >> 16;
    return (u16)r;
}

// ================= prep_all: hist+rank | cast x | cast/transpose W =========
__global__ __launch_bounds__(256) void prep_all(
    const int* __restrict__ dst, int* __restrict__ counts, int* __restrict__ rank,
    int n_edges,
    const float* __restrict__ x, u16* __restrict__ xb, int n_feat,
    const float* __restrict__ Wr, const float* __restrict__ W1,
    const float* __restrict__ W2, const float* __restrict__ W3,
    const float* __restrict__ Wop, u16* __restrict__ Wt, u16* __restrict__ Wtop,
    int HB, int CB)
{
    int b = blockIdx.x;
    if (b < HB) {
        int e = b * 256 + threadIdx.x;
        if (e < n_edges) rank[e] = atomicAdd(&counts[dst[e]], 1);
    } else if (b < HB + CB) {
        int idx = ((b - HB) * 256 + threadIdx.x) * 4;
        if (idx < n_feat) {
            float4 v = *reinterpret_cast<const float4*>(x + idx);
            ushort4 o;
            o.x = f2bf(v.x); o.y = f2bf(v.y); o.z = f2bf(v.z); o.w = f2bf(v.w);
            *reinterpret_cast<ushort4*>(xb + idx) = o;
        }
    } else {
        int i = (b - HB - CB) * 256 + threadIdx.x;
        if (i < 4 * 16384) {
            int w = i >> 14, r = i & 16383;
            int nn = r >> 7, kk = r & 127;
            const float* W = (w == 0) ? Wr : (w == 1) ? W1 : (w == 2) ? W2 : W3;
            Wt[i] = f2bf(W[kk * NF + nn]);
        } else {
            int r = i - 4 * 16384;
            if (r < 48 * 128) {
                int nn = r >> 7, kk = r & 127;
                Wtop[r] = (nn < 40) ? f2bf(Wop[kk * 40 + nn]) : (u16)0;
            }
        }
    }
}

// ====================== scans (padded-to-4 counts) =========================
__global__ __launch_bounds__(256) void scan_pass1(
    const int* __restrict__ counts, int* __restrict__ bsums, int n)
{
    __shared__ int s[256];
    int i = blockIdx.x * 256 + threadIdx.x;
    int c = (i < n) ? counts[i] : 0;
    s[threadIdx.x] = (c + 3) & ~3;
    __syncthreads();
    for (int off = 128; off > 0; off >>= 1) {
        if (threadIdx.x < off) s[threadIdx.x] += s[threadIdx.x + off];
        __syncthreads();
    }
    if (threadIdx.x == 0) bsums[blockIdx.x] = s[0];
}

__global__ __launch_bounds__(256) void scan_pass23(
    int* __restrict__ rowptr, const int* __restrict__ bsums, int n, int G)
{
    __shared__ int s[256];
    int t = threadIdx.x;
    int bv = (t < G) ? bsums[t] : 0;
    s[t] = bv;
    __syncthreads();
    for (int off = 1; off < 256; off <<= 1) {
        int u = (t >= off) ? s[t - off] : 0;
        __syncthreads();
        s[t] += u;
        __syncthreads();
    }
    int blockoff = (blockIdx.x > 0) ? s[blockIdx.x - 1] : 0;
    int total = s[255];
    __syncthreads();

    int i = blockIdx.x * 256 + t;
    int c = (i < n) ? rowptr[i] : 0;
    int v = (c + 3) & ~3;
    s[t] = v;
    __syncthreads();
    for (int off = 1; off < 256; off <<= 1) {
        int u = (t >= off) ? s[t - off] : 0;
        __syncthreads();
        s[t] += u;
        __syncthreads();
    }
    int excl = s[t] - v + blockoff;
    if (i < n) rowptr[i] = excl;
    if (i == 0) rowptr[n] = total;
}

__global__ __launch_bounds__(256) void fill_packed(
    const int* __restrict__ src, const int* __restrict__ dst,
    const float* __restrict__ ew, const int* __restrict__ rowptr,
    const int* __restrict__ rank, u32* __restrict__ ppairs, int n_edges)
{
    int e = blockIdx.x * 256 + threadIdx.x;
    if (e >= n_edges) return;
    int pos = rowptr[dst[e]] + rank[e];
    ppairs[pos] = ((u32)src[e] << 16) |
                  (u32)__half_as_ushort(__float2half_rn(ew[e]));
}

// =================== XCD-affine feature-sliced gather ======================
// block b: slice (b&7)>>1 (64B of each row), nodes [ (b>>3)*64, +64 ).
// 4 threads/node, 16B granule each. Per-XCD working set = 50k*64B = 3.2MB
// -> resident in that XCD's 4MB L2 (blockIdx%8 == XCD round-robin).
__global__ __launch_bounds__(256) void gather_slice(
    const u16* __restrict__ X, const int* __restrict__ rowptr,
    const u32* __restrict__ ppairs, u16* __restrict__ aggb, int n_nodes)
{
    const int b = blockIdx.x;
    const int slice = (b & 7) >> 1;           // 0..3
    const int t = threadIdx.x;
    const int node = (b >> 3) * 64 + (t >> 2);
    if (node >= n_nodes) return;
    const int fo = slice * 32 + (t & 3) * 8;  // u16 offset in row
    const u16* xf = X + fo;

    int e0 = rowptr[node];
    int e1 = rowptr[node + 1];
    float acc[8];
    #pragma unroll
    for (int j = 0; j < 8; j++) acc[j] = 0.f;

    int e = e0;
    for (; e + 8 <= e1; e += 8) {
        uint4 pa = *reinterpret_cast<const uint4*>(ppairs + e);
        uint4 pb = *reinterpret_cast<const uint4*>(ppairs + e + 4);
        u32 p[8] = {pa.x, pa.y, pa.z, pa.w, pb.x, pb.y, pb.z, pb.w};
        short8 v[8];
        #pragma unroll
        for (int k = 0; k < 8; k++)
            v[k] = *reinterpret_cast<const short8*>(xf + (size_t)(p[k] >> 16) * NF);
        #pragma unroll
        for (int k = 0; k < 8; k++) {
            float w = __half2float(__ushort_as_half((u16)(p[k] & 0xFFFFu)));
            #pragma unroll
            for (int j = 0; j < 8; j++)
                acc[j] = fmaf(bf2f((u16)v[k][j]), w, acc[j]);
        }
    }
    if (e < e1) {   // exactly 4 remain (rows padded to %4)
        uint4 pa = *reinterpret_cast<const uint4*>(ppairs + e);
        u32 p[4] = {pa.x, pa.y, pa.z, pa.w};
        short8 v[4];
        #pragma unroll
        for (int k = 0; k < 4; k++)
            v[k] = *reinterpret_cast<const short8*>(xf + (size_t)(p[k] >> 16) * NF);
        #pragma unroll
        for (int k = 0; k < 4; k++) {
            float w = __half2float(__ushort_as_half((u16)(p[k] & 0xFFFFu)));
            #pragma unroll
            for (int j = 0; j < 8; j++)
                acc[j] = fmaf(bf2f((u16)v[k][j]), w, acc[j]);
        }
    }

    short8 o;
    #pragma unroll
    for (int j = 0; j < 8; j++) o[j] = (short)f2bf(acc[j]);
    *reinterpret_cast<short8*>(aggb + (size_t)node * NF + fo) = o;
}

// ========================= MFMA GEMMs (bf16) ===============================
template<int RELU, int RES>
__global__ __launch_bounds__(256) void gemm_mfma128(
    const u16* __restrict__ A, const u16* __restrict__ Wt,
    const float* __restrict__ bias, const u16* __restrict__ resid,
    u16* __restrict__ out, int nrows)
{
    __shared__ u16 Bs[128 * 128];   // 32 KB, granule-XOR swizzled
    const int tid = threadIdx.x;
    #pragma unroll
    for (int i = 0; i < 8; i++) {
        int G = tid + i * 256;
        int row = G >> 4, g = G & 15, gs = g ^ (row & 7);
        *reinterpret_cast<short8*>(&Bs[row * NF + gs * 8]) =
            *reinterpret_cast<const short8*>(Wt + (size_t)G * 8);
    }

    const int wave = tid >> 6, lane = tid & 63;
    const int lrow = lane & 15, lk = lane >> 4;
    const int row0 = blockIdx.x * 64 + wave * 16;
    const int grow = row0 + lrow;

    short8 a[4];
    if (grow < nrows) {
        const u16* Ar = A + (size_t)grow * NF + lk * 8;
        #pragma unroll
        for (int t = 0; t < 4; t++)
            a[t] = *reinterpret_cast<const short8*>(Ar + t * 32);
    } else {
        #pragma unroll
        for (int t = 0; t < 4; t++)
            #pragma unroll
            for (int j = 0; j < 8; j++) a[t][j] = 0;
    }
    __syncthreads();

    f32x4 acc[8];
    #pragma unroll
    for (int c = 0; c < 8; c++) { acc[c][0]=0.f; acc[c][1]=0.f; acc[c][2]=0.f; acc[c][3]=0.f; }

    #pragma unroll
    for (int t = 0; t < 4; t++) {
        #pragma unroll
        for (int c = 0; c < 8; c++) {
            int col = c * 16 + lrow;
            int g = t * 4 + lk, gs = g ^ (col & 7);
            short8 b = *reinterpret_cast<const short8*>(&Bs[col * NF + gs * 8]);
            acc[c] = __builtin_amdgcn_mfma_f32_16x16x32_bf16(a[t], b, acc[c], 0, 0, 0);
        }
    }

    #pragma unroll
    for (int c = 0; c < 8; c++) {
        int col = c * 16 + lrow;
        float bv = bias[col];
        #pragma unroll
        for (int r = 0; r < 4; r++) {
            int orow = row0 + lk * 4 + r;
            if (orow < nrows) {
                float v = acc[c][r] + bv;
                if (RES) v += bf2f(resid[(size_t)orow * NF + col]);
                if (RELU) v = fmaxf(v, 0.f);
                out[(size_t)orow * NF + col] = f2bf(v);
            }
        }
    }
}

__global__ __launch_bounds__(256) void gemm_out40_mfma(
    const u16* __restrict__ H, const u16* __restrict__ Wtop,
    const float* __restrict__ bop, float* __restrict__ out, int nrows)
{
    __shared__ u16 Bs[48 * 128];
    const int tid = threadIdx.x;
    #pragma unroll
    for (int i = 0; i < 3; i++) {
        int G = tid + i * 256;
        int row = G >> 4, g = G & 15, gs = g ^ (row & 7);
        *reinterpret_cast<short8*>(&Bs[row * NF + gs * 8]) =
            *reinterpret_cast<const short8*>(Wtop + (size_t)G * 8);
    }

    const int wave = tid >> 6, lane = tid & 63;
    const int lrow = lane & 15, lk = lane >> 4;
    const int row0 = blockIdx.x * 64 + wave * 16;
    const int grow = row0 + lrow;

    short8 a[4];
    if (grow < nrows) {
        const u16* Hr = H + (size_t)grow * NF + lk * 8;
        #pragma unroll
        for (int t = 0; t < 4; t++)
            a[t] = *reinterpret_cast<const short8*>(Hr + t * 32);
    } else {
        #pragma unroll
        for (int t = 0; t < 4; t++)
            #pragma unroll
            for (int j = 0; j < 8; j++) a[t][j] = 0;
    }
    __syncthreads();

    f32x4 acc[3];
    #pragma unroll
    for (int c = 0; c < 3; c++) { acc[c][0]=0.f; acc[c][1]=0.f; acc[c][2]=0.f; acc[c][3]=0.f; }

    #pragma unroll
    for (int t = 0; t < 4; t++) {
        #pragma unroll
        for (int c = 0; c < 3; c++) {
            int col = c * 16 + lrow;
            int g = t * 4 + lk, gs = g ^ (col & 7);
            short8 b = *reinterpret_cast<const short8*>(&Bs[col * NF + gs * 8]);
            acc[c] = __builtin_amdgcn_mfma_f32_16x16x32_bf16(a[t], b, acc[c], 0, 0, 0);
        }
    }

    #pragma unroll
    for (int c = 0; c < 3; c++) {
        int col = c * 16 + lrow;
        if (col < 40) {
            float bv = bop[col];
            #pragma unroll
            for (int r = 0; r < 4; r++) {
                int orow = row0 + lk * 4 + r;
                if (orow < nrows)
                    out[(size_t)orow * 40 + col] = acc[c][r] + bv;
            }
        }
    }
}

// ============================== launch =====================================

extern "C" void kernel_launch(void* const* d_in, const int* in_sizes, int n_in,
                              void* d_out, int out_size, void* d_ws, size_t ws_size,
                              hipStream_t stream)
{
    const float* x   = (const float*)d_in[0];
    const int*   src = (const int*)d_in[1];
    const int*   dst = (const int*)d_in[2];
    const float* ew  = (const float*)d_in[3];
    const float* Wr  = (const float*)d_in[4];
    const float* br  = (const float*)d_in[5];
    const float* W1  = (const float*)d_in[6];
    const float* b1  = (const float*)d_in[7];
    const float* W2  = (const float*)d_in[8];
    const float* b2  = (const float*)d_in[9];
    const float* W3  = (const float*)d_in[10];
    const float* b3  = (const float*)d_in[11];
    const float* Wop = (const float*)d_in[12];
    const float* bop = (const float*)d_in[13];
    float* out = (float*)d_out;

    const int n_nodes = in_sizes[0] / NF;   // 50000
    const int n_edges = in_sizes[1];        // 640000
    const size_t feat = (size_t)n_nodes * NF;
    const int padded_cap = n_edges + 3 * n_nodes + 8;

    // workspace layout
    u16* xb   = (u16*)d_ws;
    u16* hb   = xb + feat;
    u16* aggb = hb + feat;
    u16* resb = aggb + feat;
    u16* Wt   = resb + feat;                 // 4 * 128*128
    u16* Wtop = Wt + 4 * 16384;              // 48*128
    int* rowptr = (int*)(Wtop + 48 * 128);   // n+1 (counts -> padded offsets)
    const int G1 = (n_nodes + 255) / 256;    // 196 (<=256 required)
    int* bsums  = rowptr + (n_nodes + 1);    // G1
    int* rank   = bsums + (G1 + 1);          // n_edges
    u32* ppairs = (u32*)(((uintptr_t)(rank + n_edges) + 15) & ~(uintptr_t)15);

    const int HB = (n_edges + 255) / 256;               // 2500
    const int CB = ((int)feat / 4 + 255) / 256;         // 6250
    const int PB = (4 * 16384 + 48 * 128 + 255) / 256;  // 280
    const int gemm_grid   = (n_nodes + 63) / 64;        // 782
    const int gather_grid = ((n_nodes + 63) / 64) * 8;  // 6256 (8 slices/chunk)

    // ---- CSR build (rank-based, packed, padded) + casts ----
    hipMemsetAsync(rowptr, 0, (size_t)(n_nodes + 1) * sizeof(int), stream);
    hipMemsetAsync(ppairs, 0, (size_t)padded_cap * sizeof(u32), stream);
    prep_all<<<HB + CB + PB, 256, 0, stream>>>(
        dst, rowptr, rank, n_edges, x, xb, (int)feat,
        Wr, W1, W2, W3, Wop, Wt, Wtop, HB, CB);
    scan_pass1<<<G1, 256, 0, stream>>>(rowptr, bsums, n_nodes);
    scan_pass23<<<G1, 256, 0, stream>>>(rowptr, bsums, n_nodes, G1);
    fill_packed<<<HB, 256, 0, stream>>>(src, dst, ew, rowptr, rank, ppairs, n_edges);

    // ---- res = x @ Wr + br ----
    gemm_mfma128<0, 0><<<gemm_grid, 256, 0, stream>>>(xb, Wt, br, nullptr, resb, n_nodes);

    // ---- 3 GCN layers: sliced gather -> aggb -> GEMM ----
    gather_slice<<<gather_grid, 256, 0, stream>>>(xb, rowptr, ppairs, aggb, n_nodes);
    gemm_mfma128<1, 0><<<gemm_grid, 256, 0, stream>>>(aggb, Wt + 16384, b1, nullptr, hb, n_nodes);

    gather_slice<<<gather_grid, 256, 0, stream>>>(hb, rowptr, ppairs, aggb, n_nodes);
    gemm_mfma128<1, 0><<<gemm_grid, 256, 0, stream>>>(aggb, Wt + 2 * 16384, b2, nullptr, hb, n_nodes);

    gather_slice<<<gather_grid, 256, 0, stream>>>(hb, rowptr, ppairs, aggb, n_nodes);
    gemm_mfma128<1, 1><<<gemm_grid, 256, 0, stream>>>(aggb, Wt + 3 * 16384, b3, resb, hb, n_nodes);

    // ---- output projection ----
    gemm_out40_mfma<<<gemm_grid, 256, 0, stream>>>(hb, Wtop, bop, out, n_nodes);
}

// Round 11
// 186.923 us; speedup vs baseline: 1.5753x; 1.5753x over previous
//
#include <hip/hip_runtime.h>
#include <hip/hip_fp16.h>
#include <stdint.h>

// ---------------------------------------------------------------------------
// GCN 3-layer + edge weights.
// v11: consolidation. v9 fused layers (best measured: 42.7us/layer) minus
//   binning (measured neutral); res-GEMM merged into fill launch (overlaps
//   write-bound fill with compute-bound GEMM); pad-slot zeroing inside scan
//   (drops the 2.7MB ppairs memset). 8 dispatches total.
//   Gather is MSHR*latency-bound (~4.4 TB/s effective on 164MB/layer random
//   row reads) -- structural floor ~35us/layer; fp8 rejected on accuracy.
// ---------------------------------------------------------------------------

#define NF 128

typedef unsigned short u16;
typedef unsigned int u32;
typedef __attribute__((ext_vector_type(8))) short short8;   // 8 bf16 = 16 B
typedef __attribute__((ext_vector_type(4))) float f32x4;

__device__ __forceinline__ float bf2f(u16 v) {
    union { unsigned u; float f; } x; x.u = (unsigned)v << 16; return x.f;
}
__device__ __forceinline__ u16 f2bf(float f) {
    union { float f; unsigned u; } x; x.f = f;
    unsigned r = (x.u + 0x7FFFu + ((x.u >> 16) & 1u)) >> 16;
    return (u16)r;
}

// ================= prep_all: hist+rank | cast x | cast/transpose W =========
__global__ __launch_bounds__(256) void prep_all(
    const int* __restrict__ dst, int* __restrict__ counts, int* __restrict__ rank,
    int n_edges,
    const float* __restrict__ x, u16* __restrict__ xb, int n_feat,
    const float* __restrict__ Wr, const float* __restrict__ W1,
    const float* __restrict__ W2, const float* __restrict__ W3,
    const float* __restrict__ Wop, u16* __restrict__ Wt, u16* __restrict__ Wtop,
    int HB, int CB)
{
    int b = blockIdx.x;
    if (b < HB) {
        int e = b * 256 + threadIdx.x;
        if (e < n_edges) rank[e] = atomicAdd(&counts[dst[e]], 1);
    } else if (b < HB + CB) {
        int idx = ((b - HB) * 256 + threadIdx.x) * 4;
        if (idx < n_feat) {
            float4 v = *reinterpret_cast<const float4*>(x + idx);
            ushort4 o;
            o.x = f2bf(v.x); o.y = f2bf(v.y); o.z = f2bf(v.z); o.w = f2bf(v.w);
            *reinterpret_cast<ushort4*>(xb + idx) = o;
        }
    } else {
        int i = (b - HB - CB) * 256 + threadIdx.x;
        if (i < 4 * 16384) {
            int w = i >> 14, r = i & 16383;
            int nn = r >> 7, kk = r & 127;
            const float* W = (w == 0) ? Wr : (w == 1) ? W1 : (w == 2) ? W2 : W3;
            Wt[i] = f2bf(W[kk * NF + nn]);
        } else {
            int r = i - 4 * 16384;
            if (r < 48 * 128) {
                int nn = r >> 7, kk = r & 127;
                Wtop[r] = (nn < 40) ? f2bf(Wop[kk * 40 + nn]) : (u16)0;
            }
        }
    }
}

// ====================== scans (padded-to-4 counts) =========================
__global__ __launch_bounds__(256) void scan_pass1(
    const int* __restrict__ counts, int* __restrict__ bsums, int n)
{
    __shared__ int s[256];
    int i = blockIdx.x * 256 + threadIdx.x;
    int c = (i < n) ? counts[i] : 0;
    s[threadIdx.x] = (c + 3) & ~3;
    __syncthreads();
    for (int off = 128; off > 0; off >>= 1) {
        if (threadIdx.x < off) s[threadIdx.x] += s[threadIdx.x + off];
        __syncthreads();
    }
    if (threadIdx.x == 0) bsums[blockIdx.x] = s[0];
}

// pass23: counts -> padded rowptr in place; zero the pad slots of ppairs
// (replaces the full ppairs memset; pads are deterministic per call).
__global__ __launch_bounds__(256) void scan_pass23(
    int* __restrict__ rowptr, const int* __restrict__ bsums,
    u32* __restrict__ ppairs, int n, int G)
{
    __shared__ int s[256];
    int t = threadIdx.x;
    int bv = (t < G) ? bsums[t] : 0;
    s[t] = bv;
    __syncthreads();
    for (int off = 1; off < 256; off <<= 1) {
        int u = (t >= off) ? s[t - off] : 0;
        __syncthreads();
        s[t] += u;
        __syncthreads();
    }
    int blockoff = (blockIdx.x > 0) ? s[blockIdx.x - 1] : 0;
    int total = s[255];
    __syncthreads();

    int i = blockIdx.x * 256 + t;
    int c = (i < n) ? rowptr[i] : 0;
    int v = (c + 3) & ~3;
    s[t] = v;
    __syncthreads();
    for (int off = 1; off < 256; off <<= 1) {
        int u = (t >= off) ? s[t - off] : 0;
        __syncthreads();
        s[t] += u;
        __syncthreads();
    }
    int excl = s[t] - v + blockoff;
    if (i < n) {
        rowptr[i] = excl;
        for (int k = c; k < v; ++k) ppairs[excl + k] = 0u;  // pad slots
    }
    if (i == 0) rowptr[n] = total;
}

// ============ fill (atomic-free, packed) + res-GEMM, one launch ============
// blocks [0, HB): ppairs[rowptr[dst]+rank] = (src<<16)|fp16(w)
// blocks [HB, HB+RG): res = xb @ Wt0 + br  (64 rows/block MFMA GEMM)
__global__ __launch_bounds__(256) void fill_res(
    const int* __restrict__ src, const int* __restrict__ dst,
    const float* __restrict__ ew, const int* __restrict__ rowptr,
    const int* __restrict__ rank, u32* __restrict__ ppairs, int n_edges,
    const u16* __restrict__ A, const u16* __restrict__ Wt,
    const float* __restrict__ bias, u16* __restrict__ resout, int nrows,
    int HB)
{
    __shared__ u16 Bs[128 * 128];   // used by GEMM branch only
    if (blockIdx.x < (u32)HB) {
        int e = blockIdx.x * 256 + threadIdx.x;
        if (e >= n_edges) return;
        int pos = rowptr[dst[e]] + rank[e];
        ppairs[pos] = ((u32)src[e] << 16) |
                      (u32)__half_as_ushort(__float2half_rn(ew[e]));
        return;
    }
    const int bid = blockIdx.x - HB;
    const int tid = threadIdx.x;
    #pragma unroll
    for (int i = 0; i < 8; i++) {
        int G = tid + i * 256;
        int row = G >> 4, g = G & 15, gs = g ^ (row & 7);
        *reinterpret_cast<short8*>(&Bs[row * NF + gs * 8]) =
            *reinterpret_cast<const short8*>(Wt + (size_t)G * 8);
    }

    const int wave = tid >> 6, lane = tid & 63;
    const int lrow = lane & 15, lk = lane >> 4;
    const int row0 = bid * 64 + wave * 16;
    const int grow = row0 + lrow;

    short8 a[4];
    if (grow < nrows) {
        const u16* Ar = A + (size_t)grow * NF + lk * 8;
        #pragma unroll
        for (int t = 0; t < 4; t++)
            a[t] = *reinterpret_cast<const short8*>(Ar + t * 32);
    } else {
        #pragma unroll
        for (int t = 0; t < 4; t++)
            #pragma unroll
            for (int j = 0; j < 8; j++) a[t][j] = 0;
    }
    __syncthreads();

    f32x4 acc[8];
    #pragma unroll
    for (int c = 0; c < 8; c++) { acc[c][0]=0.f; acc[c][1]=0.f; acc[c][2]=0.f; acc[c][3]=0.f; }

    #pragma unroll
    for (int t = 0; t < 4; t++) {
        #pragma unroll
        for (int c = 0; c < 8; c++) {
            int col = c * 16 + lrow;
            int g = t * 4 + lk, gs = g ^ (col & 7);
            short8 b = *reinterpret_cast<const short8*>(&Bs[col * NF + gs * 8]);
            acc[c] = __builtin_amdgcn_mfma_f32_16x16x32_bf16(a[t], b, acc[c], 0, 0, 0);
        }
    }

    #pragma unroll
    for (int c = 0; c < 8; c++) {
        int col = c * 16 + lrow;
        float bv = bias[col];
        #pragma unroll
        for (int r = 0; r < 4; r++) {
            int orow = row0 + lk * 4 + r;
            if (orow < nrows)
                resout[(size_t)orow * NF + col] = f2bf(acc[c][r] + bv);
        }
    }
}

// ================= fused layer: gather -> LDS -> MFMA ======================
// Block = 256 thr = 16 nodes. Gather: 16 lanes/node, 8-deep edge pipeline.
// MFMA: wave w -> cols [w*32,+32), B-frags straight from global Wt (L1/L2-
// resident: same 32KB every block). PROJ fuses residual+relu+128->40 proj.
template<int RES, int PROJ>
__global__ __launch_bounds__(256) void layer_gg(
    const u16* __restrict__ X, const int* __restrict__ rowptr,
    const u32* __restrict__ ppairs, const u16* __restrict__ Wt,
    const float* __restrict__ bias, const u16* __restrict__ resid,
    const u16* __restrict__ Wtop, const float* __restrict__ bop,
    u16* __restrict__ hout, float* __restrict__ out, int n_nodes)
{
    __shared__ u16 As[16 * 128];   // 4KB gathered tile, granule-XOR swizzled
    __shared__ u16 Hs[16 * 128];   // 4KB post-activation tile (PROJ only)

    const int tid = threadIdx.x;
    const int node0 = blockIdx.x * 16;

    // ---- gather phase: 16 lanes/node, 8 feats (16B) per lane ----
    {
        const int nl = tid >> 4;          // local node slot 0..15
        const int fl = tid & 15;          // feature granule 0..15
        const int node = node0 + nl;
        float acc[8];
        #pragma unroll
        for (int j = 0; j < 8; j++) acc[j] = 0.f;

        if (node < n_nodes) {
            const u16* xf = X + fl * 8;
            int e0 = rowptr[node];
            int e1 = rowptr[node + 1];
            int e = e0;
            for (; e + 8 <= e1; e += 8) {
                uint4 pa = *reinterpret_cast<const uint4*>(ppairs + e);
                uint4 pb = *reinterpret_cast<const uint4*>(ppairs + e + 4);
                u32 p[8] = {pa.x, pa.y, pa.z, pa.w, pb.x, pb.y, pb.z, pb.w};
                short8 v[8];
                #pragma unroll
                for (int k = 0; k < 8; k++)
                    v[k] = *reinterpret_cast<const short8*>(xf + (size_t)(p[k] >> 16) * NF);
                #pragma unroll
                for (int k = 0; k < 8; k++) {
                    float w = __half2float(__ushort_as_half((u16)(p[k] & 0xFFFFu)));
                    #pragma unroll
                    for (int j = 0; j < 8; j++)
                        acc[j] = fmaf(bf2f((u16)v[k][j]), w, acc[j]);
                }
            }
            if (e < e1) {   // exactly 4 remain (rows padded to %4)
                uint4 pa = *reinterpret_cast<const uint4*>(ppairs + e);
                u32 p[4] = {pa.x, pa.y, pa.z, pa.w};
                short8 v[4];
                #pragma unroll
                for (int k = 0; k < 4; k++)
                    v[k] = *reinterpret_cast<const short8*>(xf + (size_t)(p[k] >> 16) * NF);
                #pragma unroll
                for (int k = 0; k < 4; k++) {
                    float w = __half2float(__ushort_as_half((u16)(p[k] & 0xFFFFu)));
                    #pragma unroll
                    for (int j = 0; j < 8; j++)
                        acc[j] = fmaf(bf2f((u16)v[k][j]), w, acc[j]);
                }
            }
        }
        short8 o;
        #pragma unroll
        for (int j = 0; j < 8; j++) o[j] = (short)f2bf(acc[j]);
        int gs = fl ^ (nl & 7);
        *reinterpret_cast<short8*>(&As[nl * NF + gs * 8]) = o;
    }
    __syncthreads();

    // ---- MFMA phase: 16 rows x 128 cols, wave w -> cols [w*32, w*32+32) ----
    const int wave = tid >> 6, lane = tid & 63;
    const int lrow = lane & 15, lk = lane >> 4;

    short8 a[4];
    #pragma unroll
    for (int t = 0; t < 4; t++) {
        int g = t * 4 + lk, gs = g ^ (lrow & 7);
        a[t] = *reinterpret_cast<const short8*>(&As[lrow * NF + gs * 8]);
    }

    f32x4 acc2[2];
    #pragma unroll
    for (int ct = 0; ct < 2; ct++) { acc2[ct][0]=0.f; acc2[ct][1]=0.f; acc2[ct][2]=0.f; acc2[ct][3]=0.f; }

    #pragma unroll
    for (int t = 0; t < 4; t++) {
        #pragma unroll
        for (int ct = 0; ct < 2; ct++) {
            int col = wave * 32 + ct * 16 + lrow;
            short8 b = *reinterpret_cast<const short8*>(Wt + (size_t)col * NF + (t * 4 + lk) * 8);
            acc2[ct] = __builtin_amdgcn_mfma_f32_16x16x32_bf16(a[t], b, acc2[ct], 0, 0, 0);
        }
    }

    // ---- epilogue: bias (+resid) + relu; write h to global or LDS ----
    #pragma unroll
    for (int ct = 0; ct < 2; ct++) {
        int col = wave * 32 + ct * 16 + lrow;
        float bv = bias[col];
        #pragma unroll
        for (int r = 0; r < 4; r++) {
            int row = lk * 4 + r;
            int node = node0 + row;
            if (node < n_nodes) {
                float v = acc2[ct][r] + bv;
                if (RES) v += bf2f(resid[(size_t)node * NF + col]);
                v = fmaxf(v, 0.f);
                if (!PROJ) {
                    hout[(size_t)node * NF + col] = f2bf(v);
                } else {
                    Hs[row * NF + (((col >> 3) ^ (row & 7)) << 3) + (col & 7)] = f2bf(v);
                }
            }
        }
    }

    if (PROJ) {
        __syncthreads();
        // projection: wave w (w<3) -> out cols [w*16, w*16+16), K=128
        if (wave < 3) {
            short8 pa[4];
            #pragma unroll
            for (int t = 0; t < 4; t++) {
                int g = t * 4 + lk, gs = g ^ (lrow & 7);
                pa[t] = *reinterpret_cast<const short8*>(&Hs[lrow * NF + gs * 8]);
            }
            f32x4 pacc;
            pacc[0]=0.f; pacc[1]=0.f; pacc[2]=0.f; pacc[3]=0.f;
            int col = wave * 16 + lrow;
            #pragma unroll
            for (int t = 0; t < 4; t++) {
                short8 b = *reinterpret_cast<const short8*>(Wtop + (size_t)col * NF + (t * 4 + lk) * 8);
                pacc = __builtin_amdgcn_mfma_f32_16x16x32_bf16(pa[t], b, pacc, 0, 0, 0);
            }
            if (col < 40) {
                float bv = bop[col];
                #pragma unroll
                for (int r = 0; r < 4; r++) {
                    int node = node0 + lk * 4 + r;
                    if (node < n_nodes)
                        out[(size_t)node * 40 + col] = pacc[r] + bv;
                }
            }
        }
    }
}

// ============================== launch =====================================

extern "C" void kernel_launch(void* const* d_in, const int* in_sizes, int n_in,
                              void* d_out, int out_size, void* d_ws, size_t ws_size,
                              hipStream_t stream)
{
    const float* x   = (const float*)d_in[0];
    const int*   src = (const int*)d_in[1];
    const int*   dst = (const int*)d_in[2];
    const float* ew  = (const float*)d_in[3];
    const float* Wr  = (const float*)d_in[4];
    const float* br  = (const float*)d_in[5];
    const float* W1  = (const float*)d_in[6];
    const float* b1  = (const float*)d_in[7];
    const float* W2  = (const float*)d_in[8];
    const float* b2  = (const float*)d_in[9];
    const float* W3  = (const float*)d_in[10];
    const float* b3  = (const float*)d_in[11];
    const float* Wop = (const float*)d_in[12];
    const float* bop = (const float*)d_in[13];
    float* out = (float*)d_out;

    const int n_nodes = in_sizes[0] / NF;   // 50000
    const int n_edges = in_sizes[1];        // 640000
    const size_t feat = (size_t)n_nodes * NF;

    // workspace layout
    u16* xb   = (u16*)d_ws;
    u16* h1b  = xb + feat;
    u16* h2b  = h1b + feat;
    u16* resb = h2b + feat;
    u16* Wt   = resb + feat;                 // 4 * 128*128
    u16* Wtop = Wt + 4 * 16384;              // 48*128
    int* rowptr = (int*)(Wtop + 48 * 128);   // n+1 (counts -> padded offsets)
    const int G1 = (n_nodes + 255) / 256;    // 196 (<=256 required)
    int* bsums  = rowptr + (n_nodes + 1);    // G1
    int* rank   = bsums + (G1 + 1);          // n_edges
    u32* ppairs = (u32*)(((uintptr_t)(rank + n_edges) + 15) & ~(uintptr_t)15);

    const int HB = (n_edges + 255) / 256;               // 2500
    const int CB = ((int)feat / 4 + 255) / 256;         // 6250
    const int PB = (4 * 16384 + 48 * 128 + 255) / 256;  // 280
    const int RG = (n_nodes + 63) / 64;                 // 782
    const int layer_grid = (n_nodes + 15) / 16;         // 3125

    // ---- CSR build + casts (3 kernels + 1 memset) ----
    hipMemsetAsync(rowptr, 0, (size_t)(n_nodes + 1) * sizeof(int), stream);
    prep_all<<<HB + CB + PB, 256, 0, stream>>>(
        dst, rowptr, rank, n_edges, x, xb, (int)feat,
        Wr, W1, W2, W3, Wop, Wt, Wtop, HB, CB);
    scan_pass1<<<G1, 256, 0, stream>>>(rowptr, bsums, n_nodes);
    scan_pass23<<<G1, 256, 0, stream>>>(rowptr, bsums, ppairs, n_nodes, G1);

    // ---- fill ppairs + res = x @ Wr + br (one launch, overlapped) ----
    fill_res<<<HB + RG, 256, 0, stream>>>(
        src, dst, ew, rowptr, rank, ppairs, n_edges,
        xb, Wt, br, resb, n_nodes, HB);

    // ---- 3 fused GCN layers ----
    layer_gg<0, 0><<<layer_grid, 256, 0, stream>>>(
        xb, rowptr, ppairs, Wt + 16384, b1, nullptr, nullptr, nullptr,
        h1b, nullptr, n_nodes);
    layer_gg<0, 0><<<layer_grid, 256, 0, stream>>>(
        h1b, rowptr, ppairs, Wt + 2 * 16384, b2, nullptr, nullptr, nullptr,
        h2b, nullptr, n_nodes);
    layer_gg<1, 1><<<layer_grid, 256, 0, stream>>>(
        h2b, rowptr, ppairs, Wt + 3 * 16384, b3, resb, Wtop, bop,
        nullptr, out, n_nodes);
}